// Round 1
// baseline (1677.674 us; speedup 1.0000x reference)
//
#include <hip/hip_runtime.h>
#include <math.h>

#define DEV_INLINE __device__ __forceinline__

DEV_INLINE float silu_f(float v) { return v / (1.f + expf(-v)); }
DEV_INLINE float softplus_f(float v) { return (v > 20.f) ? v : log1pf(expf(v)); }

// ---------------------------------------------------------------------------
// GEMM (NT): C[m,n] = act( sum_k A[m*lda+k] * Bw[n*ldb+k] + bias[n] )
// M must be a multiple of 128 (grid.y = M/128). N arbitrary (bounds-checked).
// K must be a multiple of 16. ACT: 0=none, 1=silu, 2=softplus.
// ---------------------------------------------------------------------------
template <int ACT, int HASBIAS>
__global__ __launch_bounds__(256) void gemm_nt_128(
    const float* __restrict__ A, int lda, const float* __restrict__ Bw, int ldb,
    const float* __restrict__ bias, float* __restrict__ C, int ldc, int N, int K) {
  constexpr int BM = 128, BN = 128, BK = 16;
  __shared__ float As[BK][BM];
  __shared__ float Bs[BK][BN];
  const int tid = threadIdx.x;
  const int bm = blockIdx.y * BM;
  const int bn = blockIdx.x * BN;
  const int ty = tid >> 4, tx = tid & 15;

  float acc[8][8];
#pragma unroll
  for (int i = 0; i < 8; ++i)
#pragma unroll
    for (int j = 0; j < 8; ++j) acc[i][j] = 0.f;

  for (int k0 = 0; k0 < K; k0 += BK) {
#pragma unroll
    for (int u = 0; u < 2; ++u) {
      int f = tid + u * 256;
      int row = f >> 2;           // 0..127
      int kk = (f & 3) << 2;      // 0,4,8,12
      float4 v = *(const float4*)(A + (size_t)(bm + row) * lda + k0 + kk);
      As[kk + 0][row] = v.x; As[kk + 1][row] = v.y;
      As[kk + 2][row] = v.z; As[kk + 3][row] = v.w;
      int n = bn + row;
      float4 w = make_float4(0.f, 0.f, 0.f, 0.f);
      if (n < N) w = *(const float4*)(Bw + (size_t)n * ldb + k0 + kk);
      Bs[kk + 0][row] = w.x; Bs[kk + 1][row] = w.y;
      Bs[kk + 2][row] = w.z; Bs[kk + 3][row] = w.w;
    }
    __syncthreads();
#pragma unroll
    for (int k = 0; k < BK; ++k) {
      float a[8], b[8];
      *(float4*)&a[0] = *(const float4*)&As[k][ty * 8];
      *(float4*)&a[4] = *(const float4*)&As[k][ty * 8 + 4];
      *(float4*)&b[0] = *(const float4*)&Bs[k][tx * 8];
      *(float4*)&b[4] = *(const float4*)&Bs[k][tx * 8 + 4];
#pragma unroll
      for (int i = 0; i < 8; ++i)
#pragma unroll
        for (int j = 0; j < 8; ++j) acc[i][j] = fmaf(a[i], b[j], acc[i][j]);
    }
    __syncthreads();
  }

#pragma unroll
  for (int i = 0; i < 8; ++i) {
    int m = bm + ty * 8 + i;
#pragma unroll
    for (int j = 0; j < 8; ++j) {
      int n = bn + tx * 8 + j;
      if (n < N) {
        float v = acc[i][j];
        if (HASBIAS) v += bias[n];
        if (ACT == 1) v = silu_f(v);
        if (ACT == 2) v = softplus_f(v);
        C[(size_t)m * ldc + n] = v;
      }
    }
  }
}

// ---------------------------------------------------------------------------
// Causal depthwise conv (D_CONV=4) along L (=512) + bias + SiLU.
// in layout: [(b*512+l)*1024 + d]; out same. 16*512*1024 threads total.
// ---------------------------------------------------------------------------
__global__ __launch_bounds__(256) void conv_silu_kernel(
    const float* __restrict__ xin, const float* __restrict__ w,
    const float* __restrict__ cb, float* __restrict__ xout) {
  int idx = blockIdx.x * 256 + threadIdx.x;
  int d = idx & 1023;
  int l = (idx >> 10) & 511;
  int b = idx >> 19;
  const float* base = xin + ((size_t)b * 512) * 1024 + d;
  float acc = cb[d];
  float4 wv = *(const float4*)(w + d * 4);
  float wj[4] = {wv.x, wv.y, wv.z, wv.w};
#pragma unroll
  for (int j = 0; j < 4; ++j) {
    int ll = l - 3 + j;
    if (ll >= 0) acc = fmaf(wj[j], base[(size_t)ll * 1024], acc);
  }
  xout[idx] = silu_f(acc);
}

// ---------------------------------------------------------------------------
// Selective-scan. One thread per (b,d): sequential over l=0..511, n=0..1.
// delta_y: in = softplus delta, out = gated y (in-place, thread-owned slice).
// ---------------------------------------------------------------------------
__global__ __launch_bounds__(256) void scan_kernel(
    float* __restrict__ delta_y, const float* __restrict__ xs,
    const float* __restrict__ xdbl, const float* __restrict__ z,
    const float* __restrict__ A_log, const float* __restrict__ D_ssm) {
  int t = blockIdx.x * 256 + threadIdx.x;  // 16384 total
  int d = t & 1023;
  int b = t >> 10;
  float A0 = -expf(A_log[d * 2 + 0]);
  float A1 = -expf(A_log[d * 2 + 1]);
  float Dd = D_ssm[d];
  size_t base = (size_t)b * 512 * 1024 + d;
  size_t xb = (size_t)b * 512 * 68;
  float h0 = 0.f, h1 = 0.f;
  for (int l = 0; l < 512; ++l) {
    size_t off = base + (size_t)l * 1024;
    float dl = delta_y[off];
    float xv = xs[off];
    const float* xd = xdbl + xb + (size_t)l * 68;
    float B0 = xd[64], B1 = xd[65], C0 = xd[66], C1 = xd[67];
    h0 = fmaf(expf(dl * A0), h0, dl * B0 * xv);
    h1 = fmaf(expf(dl * A1), h1, dl * B1 * xv);
    float y = fmaf(xv, Dd, fmaf(h0, C0, h1 * C1));
    float zv = z[off];
    y *= silu_f(zv);
    delta_y[off] = y;
  }
}

// ---------------------------------------------------------------------------
// LayerNorm over last dim (1024), in-place. One block (256 thr) per row.
// ---------------------------------------------------------------------------
__global__ __launch_bounds__(256) void ln_kernel(
    float* __restrict__ y, const float* __restrict__ g, const float* __restrict__ be) {
  __shared__ float ws_[4], ws2_[4];
  size_t row = blockIdx.x;
  float* p = y + row * 1024;
  int i = threadIdx.x * 4;
  float4 v = *(const float4*)(p + i);
  float s = v.x + v.y + v.z + v.w;
  float s2 = v.x * v.x + v.y * v.y + v.z * v.z + v.w * v.w;
#pragma unroll
  for (int off = 32; off > 0; off >>= 1) {
    s += __shfl_down(s, off);
    s2 += __shfl_down(s2, off);
  }
  int wid = threadIdx.x >> 6;
  if ((threadIdx.x & 63) == 0) { ws_[wid] = s; ws2_[wid] = s2; }
  __syncthreads();
  float S = ws_[0] + ws_[1] + ws_[2] + ws_[3];
  float S2 = ws2_[0] + ws2_[1] + ws2_[2] + ws2_[3];
  float mu = S * (1.f / 1024.f);
  float var = S2 * (1.f / 1024.f) - mu * mu;
  float rstd = rsqrtf(var + 1e-5f);
  float4 gg = *(const float4*)(g + i);
  float4 bb = *(const float4*)(be + i);
  v.x = (v.x - mu) * rstd * gg.x + bb.x;
  v.y = (v.y - mu) * rstd * gg.y + bb.y;
  v.z = (v.z - mu) * rstd * gg.z + bb.z;
  v.w = (v.w - mu) * rstd * gg.w + bb.w;
  *(float4*)(p + i) = v;
}

// ---------------------------------------------------------------------------
// Fused final: per batch b, out[b][o][p] = silu(W1[o,:]·Y[b][:,p] + b1[o])
//                                        + silu(W2[o,:]·R[b][:,p] + b2[o])
// NN GEMM: M=512 (o), N=1024 (p), K=512 (c). Everything contiguous.
// ---------------------------------------------------------------------------
__global__ __launch_bounds__(256) void gemm_nn_dual(
    const float* __restrict__ W1, const float* __restrict__ W2,
    const float* __restrict__ b1, const float* __restrict__ b2,
    const float* __restrict__ Y, const float* __restrict__ R,
    float* __restrict__ out) {
  constexpr int BM = 64, BN = 128, BK = 16;
  __shared__ float As1[BK][BM], As2[BK][BM];
  __shared__ float Bs1[BK][BN], Bs2[BK][BN];
  const int b = blockIdx.z;
  const float* Yb = Y + (size_t)b * 512 * 1024;
  const float* Rb = R + (size_t)b * 512 * 1024;
  const int bm = blockIdx.y * BM;
  const int bn = blockIdx.x * BN;
  const int tid = threadIdx.x;
  const int ty = tid >> 4, tx = tid & 15;
  float acc1[4][8], acc2[4][8];
#pragma unroll
  for (int i = 0; i < 4; ++i)
#pragma unroll
    for (int j = 0; j < 8; ++j) { acc1[i][j] = 0.f; acc2[i][j] = 0.f; }

  for (int k0 = 0; k0 < 512; k0 += BK) {
    {
      int row = tid >> 2;        // 0..63
      int kk = (tid & 3) << 2;   // 0,4,8,12
      float4 v1 = *(const float4*)(W1 + (size_t)(bm + row) * 512 + k0 + kk);
      As1[kk + 0][row] = v1.x; As1[kk + 1][row] = v1.y;
      As1[kk + 2][row] = v1.z; As1[kk + 3][row] = v1.w;
      float4 v2 = *(const float4*)(W2 + (size_t)(bm + row) * 512 + k0 + kk);
      As2[kk + 0][row] = v2.x; As2[kk + 1][row] = v2.y;
      As2[kk + 2][row] = v2.z; As2[kk + 3][row] = v2.w;
    }
#pragma unroll
    for (int u = 0; u < 2; ++u) {
      int f = tid + u * 256;
      int kr = f >> 5;           // 0..15
      int nn = (f & 31) << 2;    // 0..124
      float4 v1 = *(const float4*)(Yb + (size_t)(k0 + kr) * 1024 + bn + nn);
      *(float4*)&Bs1[kr][nn] = v1;
      float4 v2 = *(const float4*)(Rb + (size_t)(k0 + kr) * 1024 + bn + nn);
      *(float4*)&Bs2[kr][nn] = v2;
    }
    __syncthreads();
#pragma unroll
    for (int k = 0; k < BK; ++k) {
      float a1[4], a2[4], q1[8], q2[8];
      *(float4*)&a1[0] = *(const float4*)&As1[k][ty * 4];
      *(float4*)&a2[0] = *(const float4*)&As2[k][ty * 4];
      *(float4*)&q1[0] = *(const float4*)&Bs1[k][tx * 8];
      *(float4*)&q1[4] = *(const float4*)&Bs1[k][tx * 8 + 4];
      *(float4*)&q2[0] = *(const float4*)&Bs2[k][tx * 8];
      *(float4*)&q2[4] = *(const float4*)&Bs2[k][tx * 8 + 4];
#pragma unroll
      for (int i = 0; i < 4; ++i)
#pragma unroll
        for (int j = 0; j < 8; ++j) {
          acc1[i][j] = fmaf(a1[i], q1[j], acc1[i][j]);
          acc2[i][j] = fmaf(a2[i], q2[j], acc2[i][j]);
        }
    }
    __syncthreads();
  }

  size_t ob = (size_t)b * 512 * 1024;
#pragma unroll
  for (int i = 0; i < 4; ++i) {
    int m = bm + ty * 4 + i;
    float bb1 = b1[m], bb2 = b2[m];
#pragma unroll
    for (int j = 0; j < 8; ++j) {
      int n = bn + tx * 8 + j;
      out[ob + (size_t)m * 1024 + n] = silu_f(acc1[i][j] + bb1) + silu_f(acc2[i][j] + bb2);
    }
  }
}

// ---------------------------------------------------------------------------
extern "C" void kernel_launch(void* const* d_in, const int* in_sizes, int n_in,
                              void* d_out, int out_size, void* d_ws, size_t ws_size,
                              hipStream_t stream) {
  const float* x          = (const float*)d_in[0];   // (16,512,32,32)
  const float* in_proj_w  = (const float*)d_in[1];   // (2048,1024)
  const float* conv_w     = (const float*)d_in[2];   // (1024,1,4)
  const float* conv_b     = (const float*)d_in[3];   // (1024)
  const float* x_proj_w   = (const float*)d_in[4];   // (68,1024)
  const float* dt_proj_w  = (const float*)d_in[5];   // (1024,64)
  const float* dt_proj_b  = (const float*)d_in[6];   // (1024)
  const float* A_log      = (const float*)d_in[7];   // (1024,2)
  const float* D_ssm      = (const float*)d_in[8];   // (1024)
  const float* out_proj_w = (const float*)d_in[9];   // (1024,1024)
  const float* ln_g       = (const float*)d_in[10];  // (1024)
  const float* ln_b       = (const float*)d_in[11];  // (1024)
  const float* lin3_w     = (const float*)d_in[12];  // (512,512)
  const float* lin3_b     = (const float*)d_in[13];  // (512)
  const float* linsp_w    = (const float*)d_in[14];  // (1024,1024)
  const float* linsp_b    = (const float*)d_in[15];  // (1024)
  const float* linres_w   = (const float*)d_in[16];  // (512,512)
  const float* linres_b   = (const float*)d_in[17];  // (512)
  float* out = (float*)d_out;

  float* ws = (float*)d_ws;
  const size_t MB8 = (size_t)8192 * 1024;
  float* bufA = ws;            // xs_pre -> delta/y_g
  float* bufB = ws + MB8;      // z      -> y_mamba (+LN)
  float* bufC = ws + 2 * MB8;  // xs     -> r_sp
  float* bufE = ws + 3 * MB8;  // x_dbl (8192 x 68)

  dim3 blk(256);
  // 1/2: in_proj split into xs_pre and z  (M=8192,N=1024,K=1024 each)
  gemm_nt_128<0, 0><<<dim3(8, 64), blk, 0, stream>>>(x, 1024, in_proj_w, 1024,
                                                     nullptr, bufA, 1024, 1024, 1024);
  gemm_nt_128<0, 0><<<dim3(8, 64), blk, 0, stream>>>(x, 1024, in_proj_w + (size_t)1024 * 1024,
                                                     1024, nullptr, bufB, 1024, 1024, 1024);
  // 3: causal depthwise conv + SiLU -> xs
  conv_silu_kernel<<<32768, blk, 0, stream>>>(bufA, conv_w, conv_b, bufC);
  // 4: x_proj -> x_dbl (N=68)
  gemm_nt_128<0, 0><<<dim3(1, 64), blk, 0, stream>>>(bufC, 1024, x_proj_w, 1024,
                                                     nullptr, bufE, 68, 68, 1024);
  // 5: dt_proj + bias + softplus -> delta (K=64, A strided lda=68)
  gemm_nt_128<2, 1><<<dim3(8, 64), blk, 0, stream>>>(bufE, 68, dt_proj_w, 64,
                                                     dt_proj_b, bufA, 1024, 1024, 64);
  // 6: selective scan + skip (D) + SiLU(z) gating, in-place in bufA
  scan_kernel<<<64, blk, 0, stream>>>(bufA, bufC, bufE, bufB, A_log, D_ssm);
  // 7: out_proj -> y_mamba (bufB; z is consumed)
  gemm_nt_128<0, 0><<<dim3(8, 64), blk, 0, stream>>>(bufA, 1024, out_proj_w, 1024,
                                                     nullptr, bufB, 1024, 1024, 1024);
  // 8: LayerNorm in-place on bufB (8192 rows x 1024)
  ln_kernel<<<8192, blk, 0, stream>>>(bufB, ln_g, ln_b);
  // 9: residual spatial linear + SiLU -> r_sp (bufC; xs is consumed)
  gemm_nt_128<1, 1><<<dim3(8, 64), blk, 0, stream>>>(x, 1024, linsp_w, 1024,
                                                     linsp_b, bufC, 1024, 1024, 1024);
  // 10: fused final dual channel-mix + SiLU + add -> out
  gemm_nn_dual<<<dim3(8, 8, 16), blk, 0, stream>>>(lin3_w, linres_w, lin3_b, linres_b,
                                                   bufB, bufC, out);
}

// Round 2
// 705.237 us; speedup vs baseline: 2.3789x; 2.3789x over previous
//
#include <hip/hip_runtime.h>
#include <math.h>

typedef __attribute__((ext_vector_type(8))) short bf16x8;
typedef __attribute__((ext_vector_type(4))) float f32x4;

#define DEV_INLINE __device__ __forceinline__

DEV_INLINE float silu_f(float v) { return v / (1.f + expf(-v)); }
DEV_INLINE float softplus_f(float v) { return (v > 20.f) ? v : log1pf(expf(v)); }
DEV_INLINE float b2f(unsigned short u) { return __uint_as_float(((unsigned int)u) << 16); }
DEV_INLINE unsigned short f2b(float f) {
  unsigned int u = __float_as_uint(f);
  return (unsigned short)((u + 0x7FFFu + ((u >> 16) & 1u)) >> 16);
}
DEV_INLINE void async16(const void* g, void* l) {
  __builtin_amdgcn_global_load_lds((const __attribute__((address_space(1))) unsigned int*)g,
                                   (__attribute__((address_space(3))) unsigned int*)l, 16, 0, 0);
}

// ---------------------------------------------------------------------------
// bf16 NT MFMA GEMM: C[m,n] = act( sum_k A[m*lda+k]*B[n*ldb+k] + bias[n] )
// BM=BN=128, BK=32, 256 thr (4 waves, 2x2), wave tile 64x64.
// LDS layout per tile: row-major [128][32] bf16 (64B rows) with slot swizzle:
//   stored slot s holds global 16B-chunk c = s ^ ((row>>1)&3)  (involution).
// XPROJ mode: N=68 logical; n<64 -> bf16 aux [m*64+n]; 64<=n<68 -> fp32 Cx[m*4+n-64].
// ---------------------------------------------------------------------------
template <int ACT, int HASBIAS, int XPROJ>
__global__ __launch_bounds__(256) void gemm_bf16_nt(
    const unsigned short* __restrict__ A, int lda,
    const unsigned short* __restrict__ B, int ldb,
    const float* __restrict__ bias,
    unsigned short* __restrict__ Cbf, int ldc,
    float* __restrict__ Cx, int K) {
  __shared__ unsigned short As[128 * 32];
  __shared__ unsigned short Bs[128 * 32];
  const int tid = threadIdx.x;
  const int w = tid >> 6, lane = tid & 63;
  const int bm = blockIdx.y * 128, bn = blockIdx.x * 128;
  const int wr = w >> 1, wc = w & 1;

  const int row0 = w * 16 + (lane >> 2);  // staging row for u=0 (+64 for u=1)
  const int s_slot = lane & 3;

  // fragment LDS byte offsets (k-invariant)
  int aoff[4], boff[4];
  const int cchunk = lane >> 4;
#pragma unroll
  for (int i = 0; i < 4; ++i) {
    int ra = wr * 64 + i * 16 + (lane & 15);
    aoff[i] = ra * 64 + ((cchunk ^ ((ra >> 1) & 3)) * 16);
    int rb = wc * 64 + i * 16 + (lane & 15);
    boff[i] = rb * 64 + ((cchunk ^ ((rb >> 1) & 3)) * 16);
  }

  f32x4 acc[4][4];
#pragma unroll
  for (int i = 0; i < 4; ++i)
#pragma unroll
    for (int j = 0; j < 4; ++j) acc[i][j] = (f32x4){0.f, 0.f, 0.f, 0.f};

  for (int k0 = 0; k0 < K; k0 += 32) {
#pragma unroll
    for (int u = 0; u < 2; ++u) {
      int row = row0 + u * 64;
      int c = s_slot ^ ((row >> 1) & 3);
      const unsigned short* ga = A + (size_t)(bm + row) * lda + k0 + c * 8;
      async16(ga, (char*)As + u * 4096 + w * 1024);
      const unsigned short* gb = B + (size_t)(bn + row) * ldb + k0 + c * 8;
      async16(gb, (char*)Bs + u * 4096 + w * 1024);
    }
    __syncthreads();
    bf16x8 af[4], bf[4];
#pragma unroll
    for (int i = 0; i < 4; ++i) {
      af[i] = *(const bf16x8*)((const char*)As + aoff[i]);
      bf[i] = *(const bf16x8*)((const char*)Bs + boff[i]);
    }
#pragma unroll
    for (int i = 0; i < 4; ++i)
#pragma unroll
      for (int j = 0; j < 4; ++j)
        acc[i][j] = __builtin_amdgcn_mfma_f32_16x16x32_bf16(af[i], bf[j], acc[i][j], 0, 0, 0);
    __syncthreads();
  }

#pragma unroll
  for (int i = 0; i < 4; ++i) {
#pragma unroll
    for (int j = 0; j < 4; ++j) {
      int ncol = bn + wc * 64 + j * 16 + (lane & 15);
      float bv = 0.f;
      if (HASBIAS) bv = bias[ncol];
#pragma unroll
      for (int r = 0; r < 4; ++r) {
        int mrow = bm + wr * 64 + i * 16 + (lane >> 4) * 4 + r;
        float v = acc[i][j][r] + bv;
        if (ACT == 1) v = silu_f(v);
        if (ACT == 2) v = softplus_f(v);
        if (XPROJ) {
          if (ncol < 64) Cbf[(size_t)mrow * 64 + ncol] = f2b(v);
          else if (ncol < 68) Cx[(size_t)mrow * 4 + (ncol - 64)] = v;
        } else {
          Cbf[(size_t)mrow * ldc + ncol] = f2b(v);
        }
      }
    }
  }
}

// ---------------------------------------------------------------------------
__global__ __launch_bounds__(256) void cast_kernel(const float* __restrict__ in,
                                                   unsigned short* __restrict__ out, int n4) {
  int i = (blockIdx.x * 256 + threadIdx.x) * 4;
  if (i < n4) {
    float4 v = *(const float4*)(in + i);
    ushort4 o;
    o.x = f2b(v.x); o.y = f2b(v.y); o.z = f2b(v.z); o.w = f2b(v.w);
    *(ushort4*)(out + i) = o;
  }
}

__global__ __launch_bounds__(256) void cast_pad_xproj(const float* __restrict__ in,
                                                      unsigned short* __restrict__ out) {
  int i = (blockIdx.x * 256 + threadIdx.x) * 4;  // 128*1024 total
  ushort4 o;
  if (i < 68 * 1024) {
    float4 v = *(const float4*)(in + i);
    o.x = f2b(v.x); o.y = f2b(v.y); o.z = f2b(v.z); o.w = f2b(v.w);
  } else {
    o.x = 0; o.y = 0; o.z = 0; o.w = 0;
  }
  *(ushort4*)(out + i) = o;
}

// ---------------------------------------------------------------------------
// Causal depthwise conv4 + bias + SiLU, bf16 in/out. Layout [(b*512+l)*1024+d].
// ---------------------------------------------------------------------------
__global__ __launch_bounds__(256) void conv_silu_bf16(
    const unsigned short* __restrict__ xin, const float* __restrict__ w,
    const float* __restrict__ cb, unsigned short* __restrict__ xout) {
  int idx = blockIdx.x * 256 + threadIdx.x;
  int d = idx & 1023;
  int l = (idx >> 10) & 511;
  int b = idx >> 19;
  const unsigned short* base = xin + ((size_t)b * 512) * 1024 + d;
  float acc = cb[d];
  float4 wv = *(const float4*)(w + d * 4);
  float wj[4] = {wv.x, wv.y, wv.z, wv.w};
#pragma unroll
  for (int j = 0; j < 4; ++j) {
    int ll = l - 3 + j;
    if (ll >= 0) acc = fmaf(wj[j], b2f(base[(size_t)ll * 1024]), acc);
  }
  xout[idx] = f2b(silu_f(acc));
}

// ---------------------------------------------------------------------------
// Selective scan, bf16 inputs, bf16 gated output. One thread per (b,d).
// BC fp32 layout [m][4] = {B0,B1,C0,C1}, m=(b*512+l).
// ---------------------------------------------------------------------------
__global__ __launch_bounds__(256) void scan_bf16(
    const unsigned short* __restrict__ delta, const unsigned short* __restrict__ xs,
    const float* __restrict__ BC, const unsigned short* __restrict__ z,
    const float* __restrict__ A_log, const float* __restrict__ D_ssm,
    unsigned short* __restrict__ yout) {
  int t = blockIdx.x * 256 + threadIdx.x;  // 16384
  int d = t & 1023;
  int b = t >> 10;
  float A0 = -expf(A_log[d * 2 + 0]);
  float A1 = -expf(A_log[d * 2 + 1]);
  float Dd = D_ssm[d];
  size_t base = (size_t)b * 512 * 1024 + d;
  size_t xb = (size_t)b * 512 * 4;
  float h0 = 0.f, h1 = 0.f;
  for (int l = 0; l < 512; ++l) {
    size_t off = base + (size_t)l * 1024;
    float dl = b2f(delta[off]);
    float xv = b2f(xs[off]);
    const float* q = BC + xb + (size_t)l * 4;
    float B0 = q[0], B1 = q[1], C0 = q[2], C1 = q[3];
    h0 = fmaf(expf(dl * A0), h0, dl * B0 * xv);
    h1 = fmaf(expf(dl * A1), h1, dl * B1 * xv);
    float y = fmaf(xv, Dd, fmaf(h0, C0, h1 * C1));
    y *= silu_f(b2f(z[off]));
    yout[off] = f2b(y);
  }
}

// ---------------------------------------------------------------------------
// LayerNorm over last dim (1024), bf16 in-place, fp32 stats.
// ---------------------------------------------------------------------------
__global__ __launch_bounds__(256) void ln_bf16(unsigned short* __restrict__ y,
                                               const float* __restrict__ g,
                                               const float* __restrict__ be) {
  __shared__ float ws_[4], ws2_[4];
  size_t row = blockIdx.x;
  unsigned short* p = y + row * 1024;
  int i = threadIdx.x * 4;
  ushort4 u = *(const ushort4*)(p + i);
  float v0 = b2f(u.x), v1 = b2f(u.y), v2 = b2f(u.z), v3 = b2f(u.w);
  float s = v0 + v1 + v2 + v3;
  float s2 = v0 * v0 + v1 * v1 + v2 * v2 + v3 * v3;
#pragma unroll
  for (int off = 32; off > 0; off >>= 1) {
    s += __shfl_down(s, off);
    s2 += __shfl_down(s2, off);
  }
  int wid = threadIdx.x >> 6;
  if ((threadIdx.x & 63) == 0) { ws_[wid] = s; ws2_[wid] = s2; }
  __syncthreads();
  float S = ws_[0] + ws_[1] + ws_[2] + ws_[3];
  float S2 = ws2_[0] + ws2_[1] + ws2_[2] + ws2_[3];
  float mu = S * (1.f / 1024.f);
  float var = S2 * (1.f / 1024.f) - mu * mu;
  float rstd = rsqrtf(var + 1e-5f);
  float4 gg = *(const float4*)(g + i);
  float4 bb = *(const float4*)(be + i);
  ushort4 o;
  o.x = f2b((v0 - mu) * rstd * gg.x + bb.x);
  o.y = f2b((v1 - mu) * rstd * gg.y + bb.y);
  o.z = f2b((v2 - mu) * rstd * gg.z + bb.z);
  o.w = f2b((v3 - mu) * rstd * gg.w + bb.w);
  *(ushort4*)(p + i) = o;
}

// ---------------------------------------------------------------------------
// Fused final dual NN GEMM (fp32 math, bf16 B operands):
// out[b][o][p] = silu(W1[o,:]·Y[b][:,p]+b1[o]) + silu(W2[o,:]·R[b][:,p]+b2[o])
// ---------------------------------------------------------------------------
__global__ __launch_bounds__(256) void gemm_nn_dual(
    const float* __restrict__ W1, const float* __restrict__ W2,
    const float* __restrict__ b1, const float* __restrict__ b2,
    const unsigned short* __restrict__ Y, const unsigned short* __restrict__ R,
    float* __restrict__ out) {
  constexpr int BM = 64, BN = 128, BK = 16;
  __shared__ float As1[BK][BM], As2[BK][BM];
  __shared__ float Bs1[BK][BN], Bs2[BK][BN];
  const int b = blockIdx.z;
  const unsigned short* Yb = Y + (size_t)b * 512 * 1024;
  const unsigned short* Rb = R + (size_t)b * 512 * 1024;
  const int bm = blockIdx.y * BM;
  const int bn = blockIdx.x * BN;
  const int tid = threadIdx.x;
  const int ty = tid >> 4, tx = tid & 15;
  float acc1[4][8], acc2[4][8];
#pragma unroll
  for (int i = 0; i < 4; ++i)
#pragma unroll
    for (int j = 0; j < 8; ++j) { acc1[i][j] = 0.f; acc2[i][j] = 0.f; }

  for (int k0 = 0; k0 < 512; k0 += BK) {
    {
      int row = tid >> 2;
      int kk = (tid & 3) << 2;
      float4 v1 = *(const float4*)(W1 + (size_t)(bm + row) * 512 + k0 + kk);
      As1[kk + 0][row] = v1.x; As1[kk + 1][row] = v1.y;
      As1[kk + 2][row] = v1.z; As1[kk + 3][row] = v1.w;
      float4 v2 = *(const float4*)(W2 + (size_t)(bm + row) * 512 + k0 + kk);
      As2[kk + 0][row] = v2.x; As2[kk + 1][row] = v2.y;
      As2[kk + 2][row] = v2.z; As2[kk + 3][row] = v2.w;
    }
#pragma unroll
    for (int u = 0; u < 2; ++u) {
      int f = tid + u * 256;
      int kr = f >> 5;
      int nn = (f & 31) << 2;
      ushort4 v1 = *(const ushort4*)(Yb + (size_t)(k0 + kr) * 1024 + bn + nn);
      Bs1[kr][nn + 0] = b2f(v1.x); Bs1[kr][nn + 1] = b2f(v1.y);
      Bs1[kr][nn + 2] = b2f(v1.z); Bs1[kr][nn + 3] = b2f(v1.w);
      ushort4 v2 = *(const ushort4*)(Rb + (size_t)(k0 + kr) * 1024 + bn + nn);
      Bs2[kr][nn + 0] = b2f(v2.x); Bs2[kr][nn + 1] = b2f(v2.y);
      Bs2[kr][nn + 2] = b2f(v2.z); Bs2[kr][nn + 3] = b2f(v2.w);
    }
    __syncthreads();
#pragma unroll
    for (int k = 0; k < BK; ++k) {
      float a1[4], a2[4], q1[8], q2[8];
      *(float4*)&a1[0] = *(const float4*)&As1[k][ty * 4];
      *(float4*)&a2[0] = *(const float4*)&As2[k][ty * 4];
      *(float4*)&q1[0] = *(const float4*)&Bs1[k][tx * 8];
      *(float4*)&q1[4] = *(const float4*)&Bs1[k][tx * 8 + 4];
      *(float4*)&q2[0] = *(const float4*)&Bs2[k][tx * 8];
      *(float4*)&q2[4] = *(const float4*)&Bs2[k][tx * 8 + 4];
#pragma unroll
      for (int i = 0; i < 4; ++i)
#pragma unroll
        for (int j = 0; j < 8; ++j) {
          acc1[i][j] = fmaf(a1[i], q1[j], acc1[i][j]);
          acc2[i][j] = fmaf(a2[i], q2[j], acc2[i][j]);
        }
    }
    __syncthreads();
  }

  size_t ob = (size_t)b * 512 * 1024;
#pragma unroll
  for (int i = 0; i < 4; ++i) {
    int m = bm + ty * 4 + i;
    float bb1 = b1[m], bb2 = b2[m];
#pragma unroll
    for (int j = 0; j < 8; ++j) {
      int n = bn + tx * 8 + j;
      out[ob + (size_t)m * 1024 + n] = silu_f(acc1[i][j] + bb1) + silu_f(acc2[i][j] + bb2);
    }
  }
}

// ---------------------------------------------------------------------------
extern "C" void kernel_launch(void* const* d_in, const int* in_sizes, int n_in,
                              void* d_out, int out_size, void* d_ws, size_t ws_size,
                              hipStream_t stream) {
  const float* x          = (const float*)d_in[0];
  const float* in_proj_w  = (const float*)d_in[1];
  const float* conv_w     = (const float*)d_in[2];
  const float* conv_b     = (const float*)d_in[3];
  const float* x_proj_w   = (const float*)d_in[4];
  const float* dt_proj_w  = (const float*)d_in[5];
  const float* dt_proj_b  = (const float*)d_in[6];
  const float* A_log      = (const float*)d_in[7];
  const float* D_ssm      = (const float*)d_in[8];
  const float* out_proj_w = (const float*)d_in[9];
  const float* ln_g       = (const float*)d_in[10];
  const float* ln_b       = (const float*)d_in[11];
  const float* lin3_w     = (const float*)d_in[12];
  const float* lin3_b     = (const float*)d_in[13];
  const float* linsp_w    = (const float*)d_in[14];
  const float* linsp_b    = (const float*)d_in[15];
  const float* linres_w   = (const float*)d_in[16];
  const float* linres_b   = (const float*)d_in[17];
  float* out = (float*)d_out;

  char* ws = (char*)d_ws;
  const size_t MB = 1024 * 1024;
  unsigned short* w_in_bf    = (unsigned short*)(ws + 0);        // 4 MB (2048x1024)
  unsigned short* w_out_bf   = (unsigned short*)(ws + 4 * MB);   // 2 MB
  unsigned short* w_linsp_bf = (unsigned short*)(ws + 6 * MB);   // 2 MB
  unsigned short* w_xp_bf    = (unsigned short*)(ws + 8 * MB);   // 256 KB (128x1024, padded)
  unsigned short* w_dt_bf    = (unsigned short*)(ws + 8 * MB + 256 * 1024);  // 128 KB
  float*          BC         = (float*)(ws + 8 * MB + 384 * 1024);           // 128 KB
  unsigned short* dtA        = (unsigned short*)(ws + 8 * MB + 512 * 1024);  // 1 MB
  unsigned short* x_bf  = (unsigned short*)(ws + 16 * MB);  // 16 MB each below
  unsigned short* seg1  = (unsigned short*)(ws + 32 * MB);  // xs_pre -> delta -> Y/LN
  unsigned short* seg2  = (unsigned short*)(ws + 48 * MB);  // z -> r_sp
  unsigned short* seg3  = (unsigned short*)(ws + 64 * MB);  // xs
  unsigned short* seg4  = (unsigned short*)(ws + 80 * MB);  // y_gated

  dim3 blk(256);
  // casts
  cast_kernel<<<2048, blk, 0, stream>>>(in_proj_w, w_in_bf, 2048 * 1024);
  cast_kernel<<<1024, blk, 0, stream>>>(out_proj_w, w_out_bf, 1024 * 1024);
  cast_kernel<<<1024, blk, 0, stream>>>(linsp_w, w_linsp_bf, 1024 * 1024);
  cast_pad_xproj<<<128, blk, 0, stream>>>(x_proj_w, w_xp_bf);
  cast_kernel<<<64, blk, 0, stream>>>(dt_proj_w, w_dt_bf, 1024 * 64);
  cast_kernel<<<8192, blk, 0, stream>>>(x, x_bf, 8192 * 1024);

  // in_proj (xs_pre, z)
  gemm_bf16_nt<0, 0, 0><<<dim3(8, 64), blk, 0, stream>>>(
      x_bf, 1024, w_in_bf, 1024, nullptr, seg1, 1024, nullptr, 1024);
  gemm_bf16_nt<0, 0, 0><<<dim3(8, 64), blk, 0, stream>>>(
      x_bf, 1024, w_in_bf + (size_t)1024 * 1024, 1024, nullptr, seg2, 1024, nullptr, 1024);
  // conv + silu -> xs
  conv_silu_bf16<<<32768, blk, 0, stream>>>(seg1, conv_w, conv_b, seg3);
  // x_proj -> dtA (bf16, n<64) + BC (fp32, n=64..67)
  gemm_bf16_nt<0, 0, 1><<<dim3(1, 64), blk, 0, stream>>>(
      seg3, 1024, w_xp_bf, 1024, nullptr, dtA, 64, BC, 1024);
  // dt_proj + bias + softplus -> delta
  gemm_bf16_nt<2, 1, 0><<<dim3(8, 64), blk, 0, stream>>>(
      dtA, 64, w_dt_bf, 64, dt_proj_b, seg1, 1024, nullptr, 64);
  // scan -> y_gated
  scan_bf16<<<64, blk, 0, stream>>>(seg1, seg3, BC, seg2, A_log, D_ssm, seg4);
  // out_proj -> Y
  gemm_bf16_nt<0, 0, 0><<<dim3(8, 64), blk, 0, stream>>>(
      seg4, 1024, w_out_bf, 1024, nullptr, seg1, 1024, nullptr, 1024);
  // LayerNorm in-place
  ln_bf16<<<8192, blk, 0, stream>>>(seg1, ln_g, ln_b);
  // residual spatial linear + silu -> r_sp
  gemm_bf16_nt<1, 1, 0><<<dim3(8, 64), blk, 0, stream>>>(
      x_bf, 1024, w_linsp_bf, 1024, linsp_b, seg2, 1024, nullptr, 1024);
  // fused final
  gemm_nn_dual<<<dim3(8, 8, 16), blk, 0, stream>>>(
      lin3_w, linres_w, lin3_b, linres_b, seg1, seg2, out);
}

// Round 3
// 579.146 us; speedup vs baseline: 2.8968x; 1.2177x over previous
//
#include <hip/hip_runtime.h>
#include <math.h>

typedef __attribute__((ext_vector_type(8))) short bf16x8;
typedef __attribute__((ext_vector_type(4))) float f32x4;

#define DEV_INLINE __device__ __forceinline__

DEV_INLINE float silu_f(float v) { return v / (1.f + expf(-v)); }
DEV_INLINE float softplus_f(float v) { return (v > 20.f) ? v : log1pf(expf(v)); }
DEV_INLINE float b2f(unsigned short u) { return __uint_as_float(((unsigned int)u) << 16); }
DEV_INLINE unsigned short f2b(float f) {
  unsigned int u = __float_as_uint(f);
  return (unsigned short)((u + 0x7FFFu + ((u >> 16) & 1u)) >> 16);
}
DEV_INLINE void async16(const void* g, void* l) {
  __builtin_amdgcn_global_load_lds((const __attribute__((address_space(1))) unsigned int*)g,
                                   (__attribute__((address_space(3))) unsigned int*)l, 16, 0, 0);
}

// ---------------------------------------------------------------------------
// bf16 NT MFMA GEMM: C[m,n] = act( sum_k A[m*lda+k]*B[n*ldb+k] + bias[n] )
// BM=BN=128, BK=32, 256 thr (4 waves 2x2), wave tile 64x64.
// LDS: row-major [128][32] bf16, slot swizzle c = s ^ ((row>>1)&3).
// XPROJ: N=68 logical; n<64 -> bf16 [m*64+n]; 64<=n<68 -> fp32 Cx[m*4+n-64].
// ---------------------------------------------------------------------------
template <int ACT, int HASBIAS, int XPROJ>
__global__ __launch_bounds__(256) void gemm_bf16_nt(
    const unsigned short* __restrict__ A, int lda,
    const unsigned short* __restrict__ B, int ldb,
    const float* __restrict__ bias,
    unsigned short* __restrict__ Cbf, int ldc,
    float* __restrict__ Cx, int K) {
  __shared__ unsigned short As[128 * 32];
  __shared__ unsigned short Bs[128 * 32];
  const int tid = threadIdx.x;
  const int w = tid >> 6, lane = tid & 63;
  const int bm = blockIdx.y * 128, bn = blockIdx.x * 128;
  const int wr = w >> 1, wc = w & 1;
  const int row0 = w * 16 + (lane >> 2);
  const int s_slot = lane & 3;

  int aoff[4], boff[4];
  const int cchunk = lane >> 4;
#pragma unroll
  for (int i = 0; i < 4; ++i) {
    int ra = wr * 64 + i * 16 + (lane & 15);
    aoff[i] = ra * 64 + ((cchunk ^ ((ra >> 1) & 3)) * 16);
    int rb = wc * 64 + i * 16 + (lane & 15);
    boff[i] = rb * 64 + ((cchunk ^ ((rb >> 1) & 3)) * 16);
  }

  f32x4 acc[4][4];
#pragma unroll
  for (int i = 0; i < 4; ++i)
#pragma unroll
    for (int j = 0; j < 4; ++j) acc[i][j] = (f32x4){0.f, 0.f, 0.f, 0.f};

  for (int k0 = 0; k0 < K; k0 += 32) {
#pragma unroll
    for (int u = 0; u < 2; ++u) {
      int row = row0 + u * 64;
      int c = s_slot ^ ((row >> 1) & 3);
      async16(A + (size_t)(bm + row) * lda + k0 + c * 8, (char*)As + u * 4096 + w * 1024);
      async16(B + (size_t)(bn + row) * ldb + k0 + c * 8, (char*)Bs + u * 4096 + w * 1024);
    }
    __syncthreads();
    bf16x8 af[4], bf[4];
#pragma unroll
    for (int i = 0; i < 4; ++i) {
      af[i] = *(const bf16x8*)((const char*)As + aoff[i]);
      bf[i] = *(const bf16x8*)((const char*)Bs + boff[i]);
    }
#pragma unroll
    for (int i = 0; i < 4; ++i)
#pragma unroll
      for (int j = 0; j < 4; ++j)
        acc[i][j] = __builtin_amdgcn_mfma_f32_16x16x32_bf16(af[i], bf[j], acc[i][j], 0, 0, 0);
    __syncthreads();
  }

#pragma unroll
  for (int i = 0; i < 4; ++i) {
#pragma unroll
    for (int j = 0; j < 4; ++j) {
      int ncol = bn + wc * 64 + j * 16 + (lane & 15);
      float bv = 0.f;
      if (HASBIAS) bv = bias[ncol];
#pragma unroll
      for (int r = 0; r < 4; ++r) {
        int mrow = bm + wr * 64 + i * 16 + (lane >> 4) * 4 + r;
        float v = acc[i][j][r] + bv;
        if (ACT == 1) v = silu_f(v);
        if (ACT == 2) v = softplus_f(v);
        if (XPROJ) {
          if (ncol < 64) Cbf[(size_t)mrow * 64 + ncol] = f2b(v);
          else if (ncol < 68) Cx[(size_t)mrow * 4 + (ncol - 64)] = v;
        } else {
          Cbf[(size_t)mrow * ldc + ncol] = f2b(v);
        }
      }
    }
  }
}

// ---------------------------------------------------------------------------
// Batched NT MFMA GEMM (shared weight A, per-batch B and C), bias per-M, bf16 out.
// C[b][m*ldc+n] = act( sum_k A[m*lda+k]*B[b][n*ldb+k] + bias[m] )
// ---------------------------------------------------------------------------
template <int ACT, int BIASM>
__global__ __launch_bounds__(256) void gemm_bf16_nt_bat(
    const unsigned short* __restrict__ A, int lda,
    const unsigned short* __restrict__ B, int ldb, size_t strideB,
    const float* __restrict__ bias,
    unsigned short* __restrict__ C, int ldc, size_t strideC, int K) {
  __shared__ unsigned short As[128 * 32];
  __shared__ unsigned short Bs[128 * 32];
  const int b = blockIdx.z;
  B += (size_t)b * strideB;
  C += (size_t)b * strideC;
  const int tid = threadIdx.x;
  const int w = tid >> 6, lane = tid & 63;
  const int bm = blockIdx.y * 128, bn = blockIdx.x * 128;
  const int wr = w >> 1, wc = w & 1;
  const int row0 = w * 16 + (lane >> 2);
  const int s_slot = lane & 3;

  int aoff[4], boff[4];
  const int cchunk = lane >> 4;
#pragma unroll
  for (int i = 0; i < 4; ++i) {
    int ra = wr * 64 + i * 16 + (lane & 15);
    aoff[i] = ra * 64 + ((cchunk ^ ((ra >> 1) & 3)) * 16);
    int rb = wc * 64 + i * 16 + (lane & 15);
    boff[i] = rb * 64 + ((cchunk ^ ((rb >> 1) & 3)) * 16);
  }

  f32x4 acc[4][4];
#pragma unroll
  for (int i = 0; i < 4; ++i)
#pragma unroll
    for (int j = 0; j < 4; ++j) acc[i][j] = (f32x4){0.f, 0.f, 0.f, 0.f};

  for (int k0 = 0; k0 < K; k0 += 32) {
#pragma unroll
    for (int u = 0; u < 2; ++u) {
      int row = row0 + u * 64;
      int c = s_slot ^ ((row >> 1) & 3);
      async16(A + (size_t)(bm + row) * lda + k0 + c * 8, (char*)As + u * 4096 + w * 1024);
      async16(B + (size_t)(bn + row) * ldb + k0 + c * 8, (char*)Bs + u * 4096 + w * 1024);
    }
    __syncthreads();
    bf16x8 af[4], bf[4];
#pragma unroll
    for (int i = 0; i < 4; ++i) {
      af[i] = *(const bf16x8*)((const char*)As + aoff[i]);
      bf[i] = *(const bf16x8*)((const char*)Bs + boff[i]);
    }
#pragma unroll
    for (int i = 0; i < 4; ++i)
#pragma unroll
      for (int j = 0; j < 4; ++j)
        acc[i][j] = __builtin_amdgcn_mfma_f32_16x16x32_bf16(af[i], bf[j], acc[i][j], 0, 0, 0);
    __syncthreads();
  }

#pragma unroll
  for (int i = 0; i < 4; ++i) {
#pragma unroll
    for (int j = 0; j < 4; ++j) {
      int ncol = bn + wc * 64 + j * 16 + (lane & 15);
#pragma unroll
      for (int r = 0; r < 4; ++r) {
        int mrow = bm + wr * 64 + i * 16 + (lane >> 4) * 4 + r;
        float v = acc[i][j][r];
        if (BIASM) v += bias[mrow];
        if (ACT == 1) v = silu_f(v);
        C[(size_t)mrow * ldc + ncol] = f2b(v);
      }
    }
  }
}

// ---------------------------------------------------------------------------
// Final dual bf16 MFMA GEMM (batched, fp32 out):
// out[b][m*1024+n] = silu(W1[m,:]·Yt[b][n,:]+b1[m]) + silu(W2[m,:]·Rt[b][n,:]+b2[m])
// M=512 (o), N=1024 (p), K=512 (c).
// ---------------------------------------------------------------------------
__global__ __launch_bounds__(256) void gemm_dual_mfma(
    const unsigned short* __restrict__ W1, const unsigned short* __restrict__ W2,
    const float* __restrict__ b1, const float* __restrict__ b2,
    const unsigned short* __restrict__ Yt, const unsigned short* __restrict__ Rt,
    float* __restrict__ out) {
  __shared__ unsigned short As1[128 * 32], As2[128 * 32];
  __shared__ unsigned short Bs1[128 * 32], Bs2[128 * 32];
  const int b = blockIdx.z;
  const unsigned short* Ytb = Yt + (size_t)b * 524288;
  const unsigned short* Rtb = Rt + (size_t)b * 524288;
  const int tid = threadIdx.x;
  const int w = tid >> 6, lane = tid & 63;
  const int bm = blockIdx.y * 128, bn = blockIdx.x * 128;
  const int wr = w >> 1, wc = w & 1;
  const int row0 = w * 16 + (lane >> 2);
  const int s_slot = lane & 3;

  int aoff[4], boff[4];
  const int cchunk = lane >> 4;
#pragma unroll
  for (int i = 0; i < 4; ++i) {
    int ra = wr * 64 + i * 16 + (lane & 15);
    aoff[i] = ra * 64 + ((cchunk ^ ((ra >> 1) & 3)) * 16);
    int rb = wc * 64 + i * 16 + (lane & 15);
    boff[i] = rb * 64 + ((cchunk ^ ((rb >> 1) & 3)) * 16);
  }

  f32x4 acc1[4][4], acc2[4][4];
#pragma unroll
  for (int i = 0; i < 4; ++i)
#pragma unroll
    for (int j = 0; j < 4; ++j) {
      acc1[i][j] = (f32x4){0.f, 0.f, 0.f, 0.f};
      acc2[i][j] = (f32x4){0.f, 0.f, 0.f, 0.f};
    }

  for (int k0 = 0; k0 < 512; k0 += 32) {
#pragma unroll
    for (int u = 0; u < 2; ++u) {
      int row = row0 + u * 64;
      int c = s_slot ^ ((row >> 1) & 3);
      async16(W1 + (size_t)(bm + row) * 512 + k0 + c * 8, (char*)As1 + u * 4096 + w * 1024);
      async16(W2 + (size_t)(bm + row) * 512 + k0 + c * 8, (char*)As2 + u * 4096 + w * 1024);
      async16(Ytb + (size_t)(bn + row) * 512 + k0 + c * 8, (char*)Bs1 + u * 4096 + w * 1024);
      async16(Rtb + (size_t)(bn + row) * 512 + k0 + c * 8, (char*)Bs2 + u * 4096 + w * 1024);
    }
    __syncthreads();
    {
      bf16x8 af[4], bf[4];
#pragma unroll
      for (int i = 0; i < 4; ++i) {
        af[i] = *(const bf16x8*)((const char*)As1 + aoff[i]);
        bf[i] = *(const bf16x8*)((const char*)Bs1 + boff[i]);
      }
#pragma unroll
      for (int i = 0; i < 4; ++i)
#pragma unroll
        for (int j = 0; j < 4; ++j)
          acc1[i][j] = __builtin_amdgcn_mfma_f32_16x16x32_bf16(af[i], bf[j], acc1[i][j], 0, 0, 0);
    }
    {
      bf16x8 af[4], bf[4];
#pragma unroll
      for (int i = 0; i < 4; ++i) {
        af[i] = *(const bf16x8*)((const char*)As2 + aoff[i]);
        bf[i] = *(const bf16x8*)((const char*)Bs2 + boff[i]);
      }
#pragma unroll
      for (int i = 0; i < 4; ++i)
#pragma unroll
        for (int j = 0; j < 4; ++j)
          acc2[i][j] = __builtin_amdgcn_mfma_f32_16x16x32_bf16(af[i], bf[j], acc2[i][j], 0, 0, 0);
    }
    __syncthreads();
  }

  float* outb = out + (size_t)b * 524288;
#pragma unroll
  for (int i = 0; i < 4; ++i) {
#pragma unroll
    for (int j = 0; j < 4; ++j) {
      int ncol = bn + wc * 64 + j * 16 + (lane & 15);
#pragma unroll
      for (int r = 0; r < 4; ++r) {
        int mrow = bm + wr * 64 + i * 16 + (lane >> 4) * 4 + r;
        float v = silu_f(acc1[i][j][r] + b1[mrow]) + silu_f(acc2[i][j][r] + b2[mrow]);
        outb[(size_t)mrow * 1024 + ncol] = v;
      }
    }
  }
}

// ---------------------------------------------------------------------------
__global__ __launch_bounds__(256) void cast_kernel(const float* __restrict__ in,
                                                   unsigned short* __restrict__ out, int n4) {
  int i = (blockIdx.x * 256 + threadIdx.x) * 4;
  if (i < n4) {
    float4 v = *(const float4*)(in + i);
    ushort4 o;
    o.x = f2b(v.x); o.y = f2b(v.y); o.z = f2b(v.z); o.w = f2b(v.w);
    *(ushort4*)(out + i) = o;
  }
}

__global__ __launch_bounds__(256) void cast_pad_xproj(const float* __restrict__ in,
                                                      unsigned short* __restrict__ out) {
  int i = (blockIdx.x * 256 + threadIdx.x) * 4;  // 128*1024 total
  ushort4 o;
  if (i < 68 * 1024) {
    float4 v = *(const float4*)(in + i);
    o.x = f2b(v.x); o.y = f2b(v.y); o.z = f2b(v.z); o.w = f2b(v.w);
  } else {
    o.x = 0; o.y = 0; o.z = 0; o.w = 0;
  }
  *(ushort4*)(out + i) = o;
}

// ---------------------------------------------------------------------------
// Causal depthwise conv4 + bias + SiLU, bf16 in/out. Layout [(b*512+l)*1024+d].
// ---------------------------------------------------------------------------
__global__ __launch_bounds__(256) void conv_silu_bf16(
    const unsigned short* __restrict__ xin, const float* __restrict__ w,
    const float* __restrict__ cb, unsigned short* __restrict__ xout) {
  int idx = blockIdx.x * 256 + threadIdx.x;
  int d = idx & 1023;
  int l = (idx >> 10) & 511;
  int b = idx >> 19;
  const unsigned short* base = xin + ((size_t)b * 512) * 1024 + d;
  float acc = cb[d];
  float4 wv = *(const float4*)(w + d * 4);
  float wj[4] = {wv.x, wv.y, wv.z, wv.w};
#pragma unroll
  for (int j = 0; j < 4; ++j) {
    int ll = l - 3 + j;
    if (ll >= 0) acc = fmaf(wj[j], b2f(base[(size_t)ll * 1024]), acc);
  }
  xout[idx] = f2b(silu_f(acc));
}

// ---------------------------------------------------------------------------
// Selective scan, bf16 in, bf16 gated out. One thread per (b,d). 64-thr blocks.
// ---------------------------------------------------------------------------
__global__ __launch_bounds__(64) void scan_bf16(
    const unsigned short* __restrict__ delta, const unsigned short* __restrict__ xs,
    const float* __restrict__ BC, const unsigned short* __restrict__ z,
    const float* __restrict__ A_log, const float* __restrict__ D_ssm,
    unsigned short* __restrict__ yout) {
  int t = blockIdx.x * 64 + threadIdx.x;  // 16384
  int d = t & 1023;
  int b = t >> 10;
  float A0 = -expf(A_log[d * 2 + 0]);
  float A1 = -expf(A_log[d * 2 + 1]);
  float Dd = D_ssm[d];
  size_t base = (size_t)b * 512 * 1024 + d;
  size_t xb = (size_t)b * 512 * 4;
  float h0 = 0.f, h1 = 0.f;
  for (int l = 0; l < 512; ++l) {
    size_t off = base + (size_t)l * 1024;
    float dl = b2f(delta[off]);
    float xv = b2f(xs[off]);
    const float* q = BC + xb + (size_t)l * 4;
    float B0 = q[0], B1 = q[1], C0 = q[2], C1 = q[3];
    h0 = fmaf(expf(dl * A0), h0, dl * B0 * xv);
    h1 = fmaf(expf(dl * A1), h1, dl * B1 * xv);
    float y = fmaf(xv, Dd, fmaf(h0, C0, h1 * C1));
    y *= silu_f(b2f(z[off]));
    yout[off] = f2b(y);
  }
}

// ---------------------------------------------------------------------------
// Column LayerNorm on Yt[b][p][c] (stats over p per (b,c); g/bias indexed by p).
// grid (8, 16): blockIdx.x = 64-wide c-chunk, blockIdx.y = b. 256 threads.
// ---------------------------------------------------------------------------
__global__ __launch_bounds__(256) void ln_col(unsigned short* __restrict__ Yt,
                                              const float* __restrict__ g,
                                              const float* __restrict__ be) {
  __shared__ float ps[4][64], ps2[4][64];
  const int b = blockIdx.y, cc = blockIdx.x * 64;
  const int cl = threadIdx.x & 63, pg = threadIdx.x >> 6;
  unsigned short* base = Yt + (size_t)b * 524288 + cc + cl;
  float s = 0.f, s2 = 0.f;
  const int p0 = pg * 256;
  for (int p = p0; p < p0 + 256; ++p) {
    float v = b2f(base[(size_t)p * 512]);
    s += v; s2 += v * v;
  }
  ps[pg][cl] = s; ps2[pg][cl] = s2;
  __syncthreads();
  float S = ps[0][cl] + ps[1][cl] + ps[2][cl] + ps[3][cl];
  float S2 = ps2[0][cl] + ps2[1][cl] + ps2[2][cl] + ps2[3][cl];
  float mu = S * (1.f / 1024.f);
  float var = S2 * (1.f / 1024.f) - mu * mu;
  float rstd = rsqrtf(var + 1e-5f);
  for (int p = p0; p < p0 + 256; ++p) {
    float v = b2f(base[(size_t)p * 512]);
    base[(size_t)p * 512] = f2b((v - mu) * rstd * g[p] + be[p]);
  }
}

// ---------------------------------------------------------------------------
extern "C" void kernel_launch(void* const* d_in, const int* in_sizes, int n_in,
                              void* d_out, int out_size, void* d_ws, size_t ws_size,
                              hipStream_t stream) {
  const float* x          = (const float*)d_in[0];
  const float* in_proj_w  = (const float*)d_in[1];
  const float* conv_w     = (const float*)d_in[2];
  const float* conv_b     = (const float*)d_in[3];
  const float* x_proj_w   = (const float*)d_in[4];
  const float* dt_proj_w  = (const float*)d_in[5];
  const float* dt_proj_b  = (const float*)d_in[6];
  const float* A_log      = (const float*)d_in[7];
  const float* D_ssm      = (const float*)d_in[8];
  const float* out_proj_w = (const float*)d_in[9];
  const float* ln_g       = (const float*)d_in[10];
  const float* ln_b       = (const float*)d_in[11];
  const float* lin3_w     = (const float*)d_in[12];
  const float* lin3_b     = (const float*)d_in[13];
  const float* linsp_w    = (const float*)d_in[14];
  const float* linsp_b    = (const float*)d_in[15];
  const float* linres_w   = (const float*)d_in[16];
  const float* linres_b   = (const float*)d_in[17];
  float* out = (float*)d_out;

  char* ws = (char*)d_ws;
  const size_t MB = 1024 * 1024;
  unsigned short* w_in_bf     = (unsigned short*)(ws + 0);                       // 4 MB
  unsigned short* w_out_bf    = (unsigned short*)(ws + 4 * MB);                  // 2 MB
  unsigned short* w_linsp_bf  = (unsigned short*)(ws + 6 * MB);                  // 2 MB
  unsigned short* w_xp_bf     = (unsigned short*)(ws + 8 * MB);                  // 256 KB
  unsigned short* w_dt_bf     = (unsigned short*)(ws + 8 * MB + 256 * 1024);     // 128 KB
  float*          BC          = (float*)(ws + 8 * MB + 384 * 1024);              // 128 KB
  unsigned short* dtA         = (unsigned short*)(ws + 8 * MB + 512 * 1024);     // 1 MB
  unsigned short* w_lin3_bf   = (unsigned short*)(ws + 10 * MB);                 // 512 KB
  unsigned short* w_linres_bf = (unsigned short*)(ws + 10 * MB + 512 * 1024);    // 512 KB
  unsigned short* x_bf  = (unsigned short*)(ws + 16 * MB);  // 16 MB
  unsigned short* seg1  = (unsigned short*)(ws + 32 * MB);  // xs_pre -> delta -> Yt
  unsigned short* seg2  = (unsigned short*)(ws + 48 * MB);  // z -> Rt
  unsigned short* seg3  = (unsigned short*)(ws + 64 * MB);  // xs
  unsigned short* seg4  = (unsigned short*)(ws + 80 * MB);  // y_gated

  dim3 blk(256);
  // casts
  cast_kernel<<<2048, blk, 0, stream>>>(in_proj_w, w_in_bf, 2048 * 1024);
  cast_kernel<<<1024, blk, 0, stream>>>(out_proj_w, w_out_bf, 1024 * 1024);
  cast_kernel<<<1024, blk, 0, stream>>>(linsp_w, w_linsp_bf, 1024 * 1024);
  cast_pad_xproj<<<128, blk, 0, stream>>>(x_proj_w, w_xp_bf);
  cast_kernel<<<64, blk, 0, stream>>>(dt_proj_w, w_dt_bf, 1024 * 64);
  cast_kernel<<<256, blk, 0, stream>>>(lin3_w, w_lin3_bf, 512 * 512);
  cast_kernel<<<256, blk, 0, stream>>>(linres_w, w_linres_bf, 512 * 512);
  cast_kernel<<<8192, blk, 0, stream>>>(x, x_bf, 8192 * 1024);

  // in_proj (xs_pre, z): M=8192 flattened
  gemm_bf16_nt<0, 0, 0><<<dim3(8, 64), blk, 0, stream>>>(
      x_bf, 1024, w_in_bf, 1024, nullptr, seg1, 1024, nullptr, 1024);
  gemm_bf16_nt<0, 0, 0><<<dim3(8, 64), blk, 0, stream>>>(
      x_bf, 1024, w_in_bf + (size_t)1024 * 1024, 1024, nullptr, seg2, 1024, nullptr, 1024);
  // conv + silu -> xs
  conv_silu_bf16<<<32768, blk, 0, stream>>>(seg1, conv_w, conv_b, seg3);
  // x_proj -> dtA (bf16) + BC (fp32)
  gemm_bf16_nt<0, 0, 1><<<dim3(1, 64), blk, 0, stream>>>(
      seg3, 1024, w_xp_bf, 1024, nullptr, dtA, 64, BC, 1024);
  // dt_proj + bias + softplus -> delta
  gemm_bf16_nt<2, 1, 0><<<dim3(8, 64), blk, 0, stream>>>(
      dtA, 64, w_dt_bf, 64, dt_proj_b, seg1, 1024, nullptr, 64);
  // scan -> y_gated
  scan_bf16<<<256, dim3(64), 0, stream>>>(seg1, seg3, BC, seg2, A_log, D_ssm, seg4);
  // out_proj, per-batch transposed: Yt[b][p][c]  (M=1024 p, N=512 c, K=1024 d)
  gemm_bf16_nt_bat<0, 0><<<dim3(4, 8, 16), blk, 0, stream>>>(
      w_out_bf, 1024, seg4, 1024, 524288, nullptr, seg1, 512, 524288, 1024);
  // column LayerNorm on Yt
  ln_col<<<dim3(8, 16), blk, 0, stream>>>(seg1, ln_g, ln_b);
  // linsp, per-batch transposed: Rt[b][p][c] = silu(W_sp·x + b[p])
  gemm_bf16_nt_bat<1, 1><<<dim3(4, 8, 16), blk, 0, stream>>>(
      w_linsp_bf, 1024, x_bf, 1024, 524288, linsp_b, seg2, 512, 524288, 1024);
  // fused final dual MFMA
  gemm_dual_mfma<<<dim3(8, 4, 16), blk, 0, stream>>>(
      w_lin3_bf, w_linres_bf, lin3_b, linres_b, seg1, seg2, out);
}

// Round 5
// 468.930 us; speedup vs baseline: 3.5777x; 1.2350x over previous
//
#include <hip/hip_runtime.h>
#include <math.h>

typedef __attribute__((ext_vector_type(8))) short bf16x8;
typedef __attribute__((ext_vector_type(4))) float f32x4;

#define DEV_INLINE __device__ __forceinline__

DEV_INLINE float silu_f(float v) { return v / (1.f + expf(-v)); }
DEV_INLINE float softplus_f(float v) { return (v > 20.f) ? v : log1pf(expf(v)); }
DEV_INLINE float b2f(unsigned short u) { return __uint_as_float(((unsigned int)u) << 16); }
DEV_INLINE unsigned short f2b(float f) {
  unsigned int u = __float_as_uint(f);
  return (unsigned short)((u + 0x7FFFu + ((u >> 16) & 1u)) >> 16);
}
DEV_INLINE void async16(const void* g, void* l) {
  __builtin_amdgcn_global_load_lds((const __attribute__((address_space(1))) unsigned int*)g,
                                   (__attribute__((address_space(3))) unsigned int*)l, 16, 0, 0);
}

// ---------------------------------------------------------------------------
// bf16 NT MFMA GEMM: C[m,n] = act( sum_k A[m*lda+k]*B[n*ldb+k] + bias[n] )
// BM=BN=128, BK=32, 256 thr (4 waves 2x2), wave tile 64x64.
// LDS: row-major [128][32] bf16, slot swizzle c = s ^ ((row>>1)&3).
// XPROJ: N=68 logical; n<64 -> bf16 [m*64+n]; 64<=n<68 -> fp32 Cx[m*4+n-64].
// ---------------------------------------------------------------------------
template <int ACT, int HASBIAS, int XPROJ>
__global__ __launch_bounds__(256) void gemm_bf16_nt(
    const unsigned short* __restrict__ A, int lda,
    const unsigned short* __restrict__ B, int ldb,
    const float* __restrict__ bias,
    unsigned short* __restrict__ Cbf, int ldc,
    float* __restrict__ Cx, int K) {
  __shared__ unsigned short As[128 * 32];
  __shared__ unsigned short Bs[128 * 32];
  const int tid = threadIdx.x;
  const int w = tid >> 6, lane = tid & 63;
  const int bm = blockIdx.y * 128, bn = blockIdx.x * 128;
  const int wr = w >> 1, wc = w & 1;
  const int row0 = w * 16 + (lane >> 2);
  const int s_slot = lane & 3;

  int aoff[4], boff[4];
  const int cchunk = lane >> 4;
#pragma unroll
  for (int i = 0; i < 4; ++i) {
    int ra = wr * 64 + i * 16 + (lane & 15);
    aoff[i] = ra * 64 + ((cchunk ^ ((ra >> 1) & 3)) * 16);
    int rb = wc * 64 + i * 16 + (lane & 15);
    boff[i] = rb * 64 + ((cchunk ^ ((rb >> 1) & 3)) * 16);
  }

  f32x4 acc[4][4];
#pragma unroll
  for (int i = 0; i < 4; ++i)
#pragma unroll
    for (int j = 0; j < 4; ++j) acc[i][j] = (f32x4){0.f, 0.f, 0.f, 0.f};

  for (int k0 = 0; k0 < K; k0 += 32) {
#pragma unroll
    for (int u = 0; u < 2; ++u) {
      int row = row0 + u * 64;
      int c = s_slot ^ ((row >> 1) & 3);
      async16(A + (size_t)(bm + row) * lda + k0 + c * 8, (char*)As + u * 4096 + w * 1024);
      async16(B + (size_t)(bn + row) * ldb + k0 + c * 8, (char*)Bs + u * 4096 + w * 1024);
    }
    __syncthreads();
    bf16x8 af[4], bf[4];
#pragma unroll
    for (int i = 0; i < 4; ++i) {
      af[i] = *(const bf16x8*)((const char*)As + aoff[i]);
      bf[i] = *(const bf16x8*)((const char*)Bs + boff[i]);
    }
#pragma unroll
    for (int i = 0; i < 4; ++i)
#pragma unroll
      for (int j = 0; j < 4; ++j)
        acc[i][j] = __builtin_amdgcn_mfma_f32_16x16x32_bf16(af[i], bf[j], acc[i][j], 0, 0, 0);
    __syncthreads();
  }

#pragma unroll
  for (int i = 0; i < 4; ++i) {
#pragma unroll
    for (int j = 0; j < 4; ++j) {
      int ncol = bn + wc * 64 + j * 16 + (lane & 15);
      float bv = 0.f;
      if (HASBIAS) bv = bias[ncol];
#pragma unroll
      for (int r = 0; r < 4; ++r) {
        int mrow = bm + wr * 64 + i * 16 + (lane >> 4) * 4 + r;
        float v = acc[i][j][r] + bv;
        if (ACT == 1) v = silu_f(v);
        if (ACT == 2) v = softplus_f(v);
        if (XPROJ) {
          if (ncol < 64) Cbf[(size_t)mrow * 64 + ncol] = f2b(v);
          else if (ncol < 68) Cx[(size_t)mrow * 4 + (ncol - 64)] = v;
        } else {
          Cbf[(size_t)mrow * ldc + ncol] = f2b(v);
        }
      }
    }
  }
}

// ---------------------------------------------------------------------------
// Batched NT MFMA GEMM (shared weight A, per-batch B and C), bias per-M, bf16 out.
// ---------------------------------------------------------------------------
template <int ACT, int BIASM>
__global__ __launch_bounds__(256) void gemm_bf16_nt_bat(
    const unsigned short* __restrict__ A, int lda,
    const unsigned short* __restrict__ B, int ldb, size_t strideB,
    const float* __restrict__ bias,
    unsigned short* __restrict__ C, int ldc, size_t strideC, int K) {
  __shared__ unsigned short As[128 * 32];
  __shared__ unsigned short Bs[128 * 32];
  const int b = blockIdx.z;
  B += (size_t)b * strideB;
  C += (size_t)b * strideC;
  const int tid = threadIdx.x;
  const int w = tid >> 6, lane = tid & 63;
  const int bm = blockIdx.y * 128, bn = blockIdx.x * 128;
  const int wr = w >> 1, wc = w & 1;
  const int row0 = w * 16 + (lane >> 2);
  const int s_slot = lane & 3;

  int aoff[4], boff[4];
  const int cchunk = lane >> 4;
#pragma unroll
  for (int i = 0; i < 4; ++i) {
    int ra = wr * 64 + i * 16 + (lane & 15);
    aoff[i] = ra * 64 + ((cchunk ^ ((ra >> 1) & 3)) * 16);
    int rb = wc * 64 + i * 16 + (lane & 15);
    boff[i] = rb * 64 + ((cchunk ^ ((rb >> 1) & 3)) * 16);
  }

  f32x4 acc[4][4];
#pragma unroll
  for (int i = 0; i < 4; ++i)
#pragma unroll
    for (int j = 0; j < 4; ++j) acc[i][j] = (f32x4){0.f, 0.f, 0.f, 0.f};

  for (int k0 = 0; k0 < K; k0 += 32) {
#pragma unroll
    for (int u = 0; u < 2; ++u) {
      int row = row0 + u * 64;
      int c = s_slot ^ ((row >> 1) & 3);
      async16(A + (size_t)(bm + row) * lda + k0 + c * 8, (char*)As + u * 4096 + w * 1024);
      async16(B + (size_t)(bn + row) * ldb + k0 + c * 8, (char*)Bs + u * 4096 + w * 1024);
    }
    __syncthreads();
    bf16x8 af[4], bf[4];
#pragma unroll
    for (int i = 0; i < 4; ++i) {
      af[i] = *(const bf16x8*)((const char*)As + aoff[i]);
      bf[i] = *(const bf16x8*)((const char*)Bs + boff[i]);
    }
#pragma unroll
    for (int i = 0; i < 4; ++i)
#pragma unroll
      for (int j = 0; j < 4; ++j)
        acc[i][j] = __builtin_amdgcn_mfma_f32_16x16x32_bf16(af[i], bf[j], acc[i][j], 0, 0, 0);
    __syncthreads();
  }

#pragma unroll
  for (int i = 0; i < 4; ++i) {
#pragma unroll
    for (int j = 0; j < 4; ++j) {
      int ncol = bn + wc * 64 + j * 16 + (lane & 15);
#pragma unroll
      for (int r = 0; r < 4; ++r) {
        int mrow = bm + wr * 64 + i * 16 + (lane >> 4) * 4 + r;
        float v = acc[i][j][r];
        if (BIASM) v += bias[mrow];
        if (ACT == 1) v = silu_f(v);
        C[(size_t)mrow * ldc + ncol] = f2b(v);
      }
    }
  }
}

// ---------------------------------------------------------------------------
// Final dual bf16 MFMA GEMM (batched, fp32 out).
// ---------------------------------------------------------------------------
__global__ __launch_bounds__(256) void gemm_dual_mfma(
    const unsigned short* __restrict__ W1, const unsigned short* __restrict__ W2,
    const float* __restrict__ b1, const float* __restrict__ b2,
    const unsigned short* __restrict__ Yt, const unsigned short* __restrict__ Rt,
    float* __restrict__ out) {
  __shared__ unsigned short As1[128 * 32], As2[128 * 32];
  __shared__ unsigned short Bs1[128 * 32], Bs2[128 * 32];
  const int b = blockIdx.z;
  const unsigned short* Ytb = Yt + (size_t)b * 524288;
  const unsigned short* Rtb = Rt + (size_t)b * 524288;
  const int tid = threadIdx.x;
  const int w = tid >> 6, lane = tid & 63;
  const int bm = blockIdx.y * 128, bn = blockIdx.x * 128;
  const int wr = w >> 1, wc = w & 1;
  const int row0 = w * 16 + (lane >> 2);
  const int s_slot = lane & 3;

  int aoff[4], boff[4];
  const int cchunk = lane >> 4;
#pragma unroll
  for (int i = 0; i < 4; ++i) {
    int ra = wr * 64 + i * 16 + (lane & 15);
    aoff[i] = ra * 64 + ((cchunk ^ ((ra >> 1) & 3)) * 16);
    int rb = wc * 64 + i * 16 + (lane & 15);
    boff[i] = rb * 64 + ((cchunk ^ ((rb >> 1) & 3)) * 16);
  }

  f32x4 acc1[4][4], acc2[4][4];
#pragma unroll
  for (int i = 0; i < 4; ++i)
#pragma unroll
    for (int j = 0; j < 4; ++j) {
      acc1[i][j] = (f32x4){0.f, 0.f, 0.f, 0.f};
      acc2[i][j] = (f32x4){0.f, 0.f, 0.f, 0.f};
    }

  for (int k0 = 0; k0 < 512; k0 += 32) {
#pragma unroll
    for (int u = 0; u < 2; ++u) {
      int row = row0 + u * 64;
      int c = s_slot ^ ((row >> 1) & 3);
      async16(W1 + (size_t)(bm + row) * 512 + k0 + c * 8, (char*)As1 + u * 4096 + w * 1024);
      async16(W2 + (size_t)(bm + row) * 512 + k0 + c * 8, (char*)As2 + u * 4096 + w * 1024);
      async16(Ytb + (size_t)(bn + row) * 512 + k0 + c * 8, (char*)Bs1 + u * 4096 + w * 1024);
      async16(Rtb + (size_t)(bn + row) * 512 + k0 + c * 8, (char*)Bs2 + u * 4096 + w * 1024);
    }
    __syncthreads();
    {
      bf16x8 af[4], bf[4];
#pragma unroll
      for (int i = 0; i < 4; ++i) {
        af[i] = *(const bf16x8*)((const char*)As1 + aoff[i]);
        bf[i] = *(const bf16x8*)((const char*)Bs1 + boff[i]);
      }
#pragma unroll
      for (int i = 0; i < 4; ++i)
#pragma unroll
        for (int j = 0; j < 4; ++j)
          acc1[i][j] = __builtin_amdgcn_mfma_f32_16x16x32_bf16(af[i], bf[j], acc1[i][j], 0, 0, 0);
    }
    {
      bf16x8 af[4], bf[4];
#pragma unroll
      for (int i = 0; i < 4; ++i) {
        af[i] = *(const bf16x8*)((const char*)As2 + aoff[i]);
        bf[i] = *(const bf16x8*)((const char*)Bs2 + boff[i]);
      }
#pragma unroll
      for (int i = 0; i < 4; ++i)
#pragma unroll
        for (int j = 0; j < 4; ++j)
          acc2[i][j] = __builtin_amdgcn_mfma_f32_16x16x32_bf16(af[i], bf[j], acc2[i][j], 0, 0, 0);
    }
    __syncthreads();
  }

  float* outb = out + (size_t)b * 524288;
#pragma unroll
  for (int i = 0; i < 4; ++i) {
#pragma unroll
    for (int j = 0; j < 4; ++j) {
      int ncol = bn + wc * 64 + j * 16 + (lane & 15);
#pragma unroll
      for (int r = 0; r < 4; ++r) {
        int mrow = bm + wr * 64 + i * 16 + (lane >> 4) * 4 + r;
        float v = silu_f(acc1[i][j][r] + b1[mrow]) + silu_f(acc2[i][j][r] + b2[mrow]);
        outb[(size_t)mrow * 1024 + ncol] = v;
      }
    }
  }
}

// ---------------------------------------------------------------------------
__global__ __launch_bounds__(256) void cast_kernel(const float* __restrict__ in,
                                                   unsigned short* __restrict__ out, int n4) {
  int i = (blockIdx.x * 256 + threadIdx.x) * 4;
  if (i < n4) {
    float4 v = *(const float4*)(in + i);
    ushort4 o;
    o.x = f2b(v.x); o.y = f2b(v.y); o.z = f2b(v.z); o.w = f2b(v.w);
    *(ushort4*)(out + i) = o;
  }
}

__global__ __launch_bounds__(256) void cast_pad_xproj(const float* __restrict__ in,
                                                      unsigned short* __restrict__ out) {
  int i = (blockIdx.x * 256 + threadIdx.x) * 4;
  ushort4 o;
  if (i < 68 * 1024) {
    float4 v = *(const float4*)(in + i);
    o.x = f2b(v.x); o.y = f2b(v.y); o.z = f2b(v.z); o.w = f2b(v.w);
  } else {
    o.x = 0; o.y = 0; o.z = 0; o.w = 0;
  }
  *(ushort4*)(out + i) = o;
}

// ---------------------------------------------------------------------------
// Causal depthwise conv4 + bias + SiLU, bf16 in/out. Layout [(b*512+l)*1024+d].
// ---------------------------------------------------------------------------
__global__ __launch_bounds__(256) void conv_silu_bf16(
    const unsigned short* __restrict__ xin, const float* __restrict__ w,
    const float* __restrict__ cb, unsigned short* __restrict__ xout) {
  int idx = blockIdx.x * 256 + threadIdx.x;
  int d = idx & 1023;
  int l = (idx >> 10) & 511;
  int b = idx >> 19;
  const unsigned short* base = xin + ((size_t)b * 512) * 1024 + d;
  float acc = cb[d];
  float4 wv = *(const float4*)(w + d * 4);
  float wj[4] = {wv.x, wv.y, wv.z, wv.w};
#pragma unroll
  for (int j = 0; j < 4; ++j) {
    int ll = l - 3 + j;
    if (ll >= 0) acc = fmaf(wj[j], b2f(base[(size_t)ll * 1024]), acc);
  }
  xout[idx] = f2b(silu_f(acc));
}

// ---------------------------------------------------------------------------
// Chunked selective scan: linear recurrence parallelized over 16 chunks of 32.
// Block = 1024 threads: 64 d-lanes x 16 chunks, per (b, d-group-of-64).
// Phase 1: per-chunk summary (P=exp(A*sum_dl), S=local end state) -> LDS.
// Phase 2: sequential combine of preceding summaries -> h_in (wave-uniform).
// Phase 3: rerun chunk from h_in (loads L2-hot), gate with SiLU(z), write bf16.
// ---------------------------------------------------------------------------
__global__ __launch_bounds__(1024) void scan_chunked(
    const unsigned short* __restrict__ delta, const unsigned short* __restrict__ xs,
    const float* __restrict__ BC, const unsigned short* __restrict__ z,
    const float* __restrict__ A_log, const float* __restrict__ D_ssm,
    unsigned short* __restrict__ yout) {
  __shared__ float4 ps[16][64];
  const int d_l = threadIdx.x & 63;
  const int ck = threadIdx.x >> 6;  // 0..15
  const int b = blockIdx.y;
  const int d = blockIdx.x * 64 + d_l;
  const float A0 = -expf(A_log[d * 2 + 0]);
  const float A1 = -expf(A_log[d * 2 + 1]);
  const size_t base = ((size_t)b * 512 + ck * 32) * 1024 + d;
  const size_t bcb = ((size_t)b * 512 + ck * 32) * 4;

  float h0 = 0.f, h1 = 0.f, sumdl = 0.f;
  for (int i = 0; i < 32; ++i) {
    size_t off = base + (size_t)i * 1024;
    float dl = b2f(delta[off]);
    float xv = b2f(xs[off]);
    const float* q = BC + bcb + i * 4;
    sumdl += dl;
    float dx = dl * xv;
    h0 = fmaf(expf(dl * A0), h0, dx * q[0]);
    h1 = fmaf(expf(dl * A1), h1, dx * q[1]);
  }
  ps[ck][d_l] = make_float4(expf(A0 * sumdl), expf(A1 * sumdl), h0, h1);
  __syncthreads();

  h0 = 0.f; h1 = 0.f;
  for (int k = 0; k < ck; ++k) {
    float4 s = ps[k][d_l];
    h0 = fmaf(s.x, h0, s.z);
    h1 = fmaf(s.y, h1, s.w);
  }

  const float Dd = D_ssm[d];
  for (int i = 0; i < 32; ++i) {
    size_t off = base + (size_t)i * 1024;
    float dl = b2f(delta[off]);
    float xv = b2f(xs[off]);
    const float* q = BC + bcb + i * 4;
    float dx = dl * xv;
    h0 = fmaf(expf(dl * A0), h0, dx * q[0]);
    h1 = fmaf(expf(dl * A1), h1, dx * q[1]);
    float y = fmaf(xv, Dd, fmaf(h0, q[2], h1 * q[3]));
    y *= silu_f(b2f(z[off]));
    yout[off] = f2b(y);
  }
}

// ---------------------------------------------------------------------------
// Column LayerNorm on Yt[b][p][c] (stats over p per (b,c); g/bias indexed by p).
// ---------------------------------------------------------------------------
__global__ __launch_bounds__(256) void ln_col(unsigned short* __restrict__ Yt,
                                              const float* __restrict__ g,
                                              const float* __restrict__ be) {
  __shared__ float ps[4][64], ps2[4][64];
  const int b = blockIdx.y, cc = blockIdx.x * 64;
  const int cl = threadIdx.x & 63, pg = threadIdx.x >> 6;
  unsigned short* base = Yt + (size_t)b * 524288 + cc + cl;
  float s = 0.f, s2 = 0.f;
  const int p0 = pg * 256;
  for (int p = p0; p < p0 + 256; ++p) {
    float v = b2f(base[(size_t)p * 512]);
    s += v; s2 += v * v;
  }
  ps[pg][cl] = s; ps2[pg][cl] = s2;
  __syncthreads();
  float S = ps[0][cl] + ps[1][cl] + ps[2][cl] + ps[3][cl];
  float S2 = ps2[0][cl] + ps2[1][cl] + ps2[2][cl] + ps2[3][cl];
  float mu = S * (1.f / 1024.f);
  float var = S2 * (1.f / 1024.f) - mu * mu;
  float rstd = rsqrtf(var + 1e-5f);
  for (int p = p0; p < p0 + 256; ++p) {
    float v = b2f(base[(size_t)p * 512]);
    base[(size_t)p * 512] = f2b((v - mu) * rstd * g[p] + be[p]);
  }
}

// ---------------------------------------------------------------------------
extern "C" void kernel_launch(void* const* d_in, const int* in_sizes, int n_in,
                              void* d_out, int out_size, void* d_ws, size_t ws_size,
                              hipStream_t stream) {
  const float* x          = (const float*)d_in[0];
  const float* in_proj_w  = (const float*)d_in[1];
  const float* conv_w     = (const float*)d_in[2];
  const float* conv_b     = (const float*)d_in[3];
  const float* x_proj_w   = (const float*)d_in[4];
  const float* dt_proj_w  = (const float*)d_in[5];
  const float* dt_proj_b  = (const float*)d_in[6];
  const float* A_log      = (const float*)d_in[7];
  const float* D_ssm      = (const float*)d_in[8];
  const float* out_proj_w = (const float*)d_in[9];
  const float* ln_g       = (const float*)d_in[10];
  const float* ln_b       = (const float*)d_in[11];
  const float* lin3_w     = (const float*)d_in[12];
  const float* lin3_b     = (const float*)d_in[13];
  const float* linsp_w    = (const float*)d_in[14];
  const float* linsp_b    = (const float*)d_in[15];
  const float* linres_w   = (const float*)d_in[16];
  const float* linres_b   = (const float*)d_in[17];
  float* out = (float*)d_out;

  char* ws = (char*)d_ws;
  const size_t MB = 1024 * 1024;
  unsigned short* w_in_bf     = (unsigned short*)(ws + 0);                       // 4 MB
  unsigned short* w_out_bf    = (unsigned short*)(ws + 4 * MB);                  // 2 MB
  unsigned short* w_linsp_bf  = (unsigned short*)(ws + 6 * MB);                  // 2 MB
  unsigned short* w_xp_bf     = (unsigned short*)(ws + 8 * MB);                  // 256 KB
  unsigned short* w_dt_bf     = (unsigned short*)(ws + 8 * MB + 256 * 1024);     // 128 KB
  float*          BC          = (float*)(ws + 8 * MB + 384 * 1024);              // 128 KB
  unsigned short* dtA         = (unsigned short*)(ws + 8 * MB + 512 * 1024);     // 1 MB
  unsigned short* w_lin3_bf   = (unsigned short*)(ws + 10 * MB);                 // 512 KB
  unsigned short* w_linres_bf = (unsigned short*)(ws + 10 * MB + 512 * 1024);    // 512 KB
  unsigned short* x_bf  = (unsigned short*)(ws + 16 * MB);  // 16 MB
  unsigned short* seg1  = (unsigned short*)(ws + 32 * MB);  // xs_pre -> delta -> Yt
  unsigned short* seg2  = (unsigned short*)(ws + 48 * MB);  // z -> Rt
  unsigned short* seg3  = (unsigned short*)(ws + 64 * MB);  // xs
  unsigned short* seg4  = (unsigned short*)(ws + 80 * MB);  // y_gated

  dim3 blk(256);
  // casts
  cast_kernel<<<2048, blk, 0, stream>>>(in_proj_w, w_in_bf, 2048 * 1024);
  cast_kernel<<<1024, blk, 0, stream>>>(out_proj_w, w_out_bf, 1024 * 1024);
  cast_kernel<<<1024, blk, 0, stream>>>(linsp_w, w_linsp_bf, 1024 * 1024);
  cast_pad_xproj<<<128, blk, 0, stream>>>(x_proj_w, w_xp_bf);
  cast_kernel<<<64, blk, 0, stream>>>(dt_proj_w, w_dt_bf, 1024 * 64);
  cast_kernel<<<256, blk, 0, stream>>>(lin3_w, w_lin3_bf, 512 * 512);
  cast_kernel<<<256, blk, 0, stream>>>(linres_w, w_linres_bf, 512 * 512);
  cast_kernel<<<8192, blk, 0, stream>>>(x, x_bf, 8192 * 1024);

  // in_proj (xs_pre, z)
  gemm_bf16_nt<0, 0, 0><<<dim3(8, 64), blk, 0, stream>>>(
      x_bf, 1024, w_in_bf, 1024, nullptr, seg1, 1024, nullptr, 1024);
  gemm_bf16_nt<0, 0, 0><<<dim3(8, 64), blk, 0, stream>>>(
      x_bf, 1024, w_in_bf + (size_t)1024 * 1024, 1024, nullptr, seg2, 1024, nullptr, 1024);
  // conv + silu -> xs
  conv_silu_bf16<<<32768, blk, 0, stream>>>(seg1, conv_w, conv_b, seg3);
  // x_proj -> dtA (bf16) + BC (fp32)
  gemm_bf16_nt<0, 0, 1><<<dim3(1, 64), blk, 0, stream>>>(
      seg3, 1024, w_xp_bf, 1024, nullptr, dtA, 64, BC, 1024);
  // dt_proj + bias + softplus -> delta
  gemm_bf16_nt<2, 1, 0><<<dim3(8, 64), blk, 0, stream>>>(
      dtA, 64, w_dt_bf, 64, dt_proj_b, seg1, 1024, nullptr, 64);
  // chunked scan -> y_gated
  scan_chunked<<<dim3(16, 16), dim3(1024), 0, stream>>>(
      seg1, seg3, BC, seg2, A_log, D_ssm, seg4);
  // out_proj, per-batch transposed: Yt[b][p][c]
  gemm_bf16_nt_bat<0, 0><<<dim3(4, 8, 16), blk, 0, stream>>>(
      w_out_bf, 1024, seg4, 1024, 524288, nullptr, seg1, 512, 524288, 1024);
  // column LayerNorm on Yt
  ln_col<<<dim3(8, 16), blk, 0, stream>>>(seg1, ln_g, ln_b);
  // linsp, per-batch transposed: Rt[b][p][c] = silu(W_sp·x + b[p])
  gemm_bf16_nt_bat<1, 1><<<dim3(4, 8, 16), blk, 0, stream>>>(
      w_linsp_bf, 1024, x_bf, 1024, 524288, linsp_b, seg2, 512, 524288, 1024);
  // fused final dual MFMA
  gemm_dual_mfma<<<dim3(8, 4, 16), blk, 0, stream>>>(
      w_lin3_bf, w_linres_bf, lin3_b, linres_b, seg1, seg2, out);
}